// Round 1
// 238.663 us; speedup vs baseline: 1.1317x; 1.1317x over previous
//
#include <hip/hip_runtime.h>
#include <hip/hip_bf16.h>
#include <cstdint>

#define TOKENS 8192
#define DIN 1024
#define DOUT 1024
#define NE 8

typedef __bf16 bf16;
typedef __attribute__((ext_vector_type(8))) __bf16 bf16x8;
typedef __attribute__((ext_vector_type(4))) float floatx4;
typedef __attribute__((ext_vector_type(2))) float floatx2;

// async global->LDS, 16B per lane. LDS dest must be wave-uniform base + lane*16.
__device__ __forceinline__ void async16(const void* gptr, void* lptr) {
  __builtin_amdgcn_global_load_lds(
      (const __attribute__((address_space(1))) void*)gptr,
      (__attribute__((address_space(3))) void*)lptr,
      16, 0, 0);
}

// ---------------------------------------------------------------------------
// Fused prep. R7: gate path rewritten — old version had every wave gather the
// full 32KB gate_w with 64B-stride loads (64 cache lines per instruction,
// L1-serialized => ~100us). Now: gate_w is staged TRANSPOSED into LDS once per
// block (coalesced), 16 tokens/block (4 waves x 4 tokens), weights read via
// conflict-free ds_read_b128, x read as floatx4 (16B/lane).
// Blocks [0,512)   = gate softmax + x->bf16 (16 tokens each).
// Blocks [512,2560) = W[e][i][o] fp32 -> Wt[e][o][i] bf16 transpose (as R6).
// ---------------------------------------------------------------------------
__global__ __launch_bounds__(256) void prep_kernel(
    const float* __restrict__ x, const float* __restrict__ gw,
    const float* __restrict__ gb, float* __restrict__ g,
    bf16* __restrict__ xb, const float* __restrict__ w,
    bf16* __restrict__ wt) {
  __shared__ __align__(16) float smem[NE * DIN];  // 32 KB

  if (blockIdx.x < 512) {
    const int tid = threadIdx.x;
    // Stage gw transposed: smem[e*1024 + i] = gw[i*8 + e]. Coalesced 16B reads.
#pragma unroll
    for (int k = 0; k < 8; ++k) {
      const int base = (k * 256 + tid) * 4;  // flat float index into gw
      const floatx4 v = *(const floatx4*)(gw + base);
#pragma unroll
      for (int m = 0; m < 4; ++m) {
        const int j = base + m;
        smem[(j & 7) * DIN + (j >> 3)] = v[m];
      }
    }
    __syncthreads();

    const int lane = tid & 63;
    const int wave = tid >> 6;
#pragma unroll
    for (int tt = 0; tt < 4; ++tt) {
      const int t = blockIdx.x * 16 + wave * 4 + tt;
      const float* xr = x + (size_t)t * DIN;
      bf16* xbr = xb + (size_t)t * DIN;

      float acc[NE];
#pragma unroll
      for (int e = 0; e < NE; ++e) acc[e] = 0.f;

#pragma unroll
      for (int it = 0; it < 4; ++it) {
        const int i = it * 256 + lane * 4;
        const floatx4 xv = *(const floatx4*)(xr + i);
        union { bf16 b[4]; uint64_t u; } cv;
#pragma unroll
        for (int m = 0; m < 4; ++m) cv.b[m] = (bf16)xv[m];
        *(uint64_t*)(xbr + i) = cv.u;
#pragma unroll
        for (int e = 0; e < NE; ++e) {
          const floatx4 wv = *(const floatx4*)(smem + e * DIN + i);
          acc[e] += xv[0] * wv[0] + xv[1] * wv[1] + xv[2] * wv[2] + xv[3] * wv[3];
        }
      }
#pragma unroll
      for (int e = 0; e < NE; ++e)
#pragma unroll
        for (int off = 32; off > 0; off >>= 1)
          acc[e] += __shfl_xor(acc[e], off, 64);

      float lg[NE];
      float mx = -3.0e38f;
#pragma unroll
      for (int e = 0; e < NE; ++e) { lg[e] = acc[e] + gb[e]; mx = fmaxf(mx, lg[e]); }
      float s = 0.f;
#pragma unroll
      for (int e = 0; e < NE; ++e) { lg[e] = __expf(lg[e] - mx); s += lg[e]; }
      const float inv = 1.f / s;
      if (lane == 0) {
        floatx4 o0, o1;
#pragma unroll
        for (int e = 0; e < 4; ++e) { o0[e] = lg[e] * inv; o1[e] = lg[e + 4] * inv; }
        *(floatx4*)(g + (size_t)t * NE) = o0;
        *(floatx4*)(g + (size_t)t * NE + 4) = o1;
      }
    }
  } else {
    float (*tile)[65] = (float(*)[65])smem;  // 64*65*4 = 16.6 KB of smem
    const int b = blockIdx.x - 512;
    const int e = b >> 8;
    const int i0 = ((b >> 4) & 15) * 64;
    const int o0 = (b & 15) * 64;
    const int tid = threadIdx.x;
    const int c4 = (tid & 15) * 4;
    const int r = tid >> 4;

    const float* src = w + ((size_t)e * DIN + i0) * DOUT + o0;
#pragma unroll
    for (int rr = r; rr < 64; rr += 16) {
      const floatx4 v = *(const floatx4*)(src + (size_t)rr * DOUT + c4);
      tile[rr][c4] = v[0]; tile[rr][c4 + 1] = v[1];
      tile[rr][c4 + 2] = v[2]; tile[rr][c4 + 3] = v[3];
    }
    __syncthreads();
    bf16* dst = wt + ((size_t)e * DOUT + o0) * DIN + i0;
#pragma unroll
    for (int rr = r; rr < 64; rr += 16) {
      union { bf16 b[4]; uint64_t u; } cv;
#pragma unroll
      for (int j = 0; j < 4; ++j) cv.b[j] = (bf16)tile[c4 + j][rr];
      *(uint64_t*)(dst + (size_t)rr * DIN + c4) = cv.u;
    }
  }
}

// ---------------------------------------------------------------------------
// Fused MoE GEMM (structure unchanged from R6, 161.8us / MfmaUtil 37.5%).
// R7 adds an XCD-aware block swizzle: under round-robin XCD assignment
// (idx%8), old mapping pinned bn to an XCD => every A panel fetched by all 8
// XCDs (FETCH 543MB vs 67MB unique). New mapping gives each XCD a 16bm x 4bn
// chunk: dupA=2, dupB=4, per-XCD per-expert working set ~5MB (~L2).
// BK=128: 64 MFMA per wave per barrier, 8 barrier windows per expert.
// LDS 2 x 32KB = 64KB/block (2 blocks/CU).
// ---------------------------------------------------------------------------
__global__ __launch_bounds__(256, 2) void moe_gemm(
    const bf16* __restrict__ xb, const bf16* __restrict__ wt,
    const float* __restrict__ g, float* __restrict__ out) {
  __shared__ __align__(16) bf16 As[128 * 128];  // 32KB
  __shared__ __align__(16) bf16 Bs[128 * 128];  // 32KB

  const int tid = threadIdx.x;
  // XCD swizzle: c = idx&7 (XCD under round-robin), j = idx>>3 in [0,64).
  // bm = (c>>1)*16 + (j&15), bn = (c&1)*4 + (j>>4). Bijective on 512 blocks.
  const int c = blockIdx.x & 7;
  const int jj = blockIdx.x >> 3;
  const int bm = (c >> 1) * 16 + (jj & 15);
  const int bn = (c & 1) * 4 + (jj >> 4);
  const int lane = tid & 63;
  const int wave = tid >> 6;
  const int wm = wave >> 1, wn = wave & 1;
  const int lr = lane & 15, lq = lane >> 4;

  // staging: pass j writes 16B-units {tid + 256j}; unit u -> row = u>>4
  // (= srow + 16j), pos = u&15, global col = (pos ^ (row&7))*8; row&7
  // invariant across j (16j === 0 mod 8).
  const int srow = tid >> 4;                                  // 0..15
  const int scol = (((tid & 15) ^ (srow & 7)) << 3);          // swizzled col

  const bf16* agp = xb + ((size_t)(bm * 128 + srow)) * DIN + scol;
  bf16* const alp = As + tid * 8;
  bf16* const blp = Bs + tid * 8;

  // fragment read: elem offset = row*128 + ((h*4+lq)^(lr&7))*8
  const int kx = lr & 7;

  const floatx4 fzero = {0.f, 0.f, 0.f, 0.f};
  floatx4 accF[4][4];
#pragma unroll
  for (int im = 0; im < 4; ++im)
#pragma unroll
    for (int in = 0; in < 4; ++in) accF[im][in] = fzero;

  const int tok0 = bm * 128 + wm * 64;

  for (int e = 0; e < NE; ++e) {
    const bf16* bgp = wt + ((size_t)e << 20) +
                      ((size_t)(bn * 128 + srow)) * DIN + scol;
    floatx4 accE[4][4];
#pragma unroll
    for (int im = 0; im < 4; ++im)
#pragma unroll
      for (int in = 0; in < 4; ++in) accE[im][in] = fzero;

    for (int k0 = 0; k0 < DIN; k0 += 128) {
      __syncthreads();
#pragma unroll
      for (int j = 0; j < 8; ++j) {
        // pass j: byte offset j*4096 = element offset j*2048
        async16(agp + k0 + (size_t)(16 * j) * DIN, alp + j * 2048);
        async16(bgp + k0 + (size_t)(16 * j) * DIN, blp + j * 2048);
      }
      __syncthreads();

#pragma unroll
      for (int h = 0; h < 4; ++h) {
        const int kg = ((h * 4 + lq) ^ kx) << 3;
        bf16x8 av[4], bv[4];
#pragma unroll
        for (int im = 0; im < 4; ++im)
          av[im] = *(const bf16x8*)(As + (wm * 64 + im * 16 + lr) * 128 + kg);
#pragma unroll
        for (int in = 0; in < 4; ++in)
          bv[in] = *(const bf16x8*)(Bs + (wn * 64 + in * 16 + lr) * 128 + kg);
#pragma unroll
        for (int im = 0; im < 4; ++im)
#pragma unroll
          for (int in = 0; in < 4; ++in)
            accE[im][in] = __builtin_amdgcn_mfma_f32_16x16x32_bf16(
                av[im], bv[in], accE[im][in], 0, 0, 0);
      }
    }

    // fold: accF += g[row, e] * accE
#pragma unroll
    for (int im = 0; im < 4; ++im) {
      float gv[4];
#pragma unroll
      for (int r = 0; r < 4; ++r)
        gv[r] = g[(size_t)(tok0 + im * 16 + lq * 4 + r) * NE + e];
#pragma unroll
      for (int in = 0; in < 4; ++in)
#pragma unroll
        for (int r = 0; r < 4; ++r)
          accF[im][in][r] += gv[r] * accE[im][in][r];
    }
  }

#pragma unroll
  for (int im = 0; im < 4; ++im)
#pragma unroll
    for (int in = 0; in < 4; ++in) {
      const int col = bn * 128 + wn * 64 + in * 16 + lr;
#pragma unroll
      for (int r = 0; r < 4; ++r)
        out[(size_t)(tok0 + im * 16 + lq * 4 + r) * DOUT + col] =
            accF[im][in][r];
    }
}

// ---------------------------------------------------------------------------
extern "C" void kernel_launch(void* const* d_in, const int* in_sizes, int n_in,
                              void* d_out, int out_size, void* d_ws,
                              size_t ws_size, hipStream_t stream) {
  const float* x  = (const float*)d_in[0];
  const float* gw = (const float*)d_in[1];
  const float* gb = (const float*)d_in[2];
  const float* w  = (const float*)d_in[3];
  float* out = (float*)d_out;

  char* ws = (char*)d_ws;
  float* g  = (float*)ws;
  bf16* xb  = (bf16*)(ws + 262144);
  bf16* wt  = (bf16*)(ws + 262144 + (size_t)TOKENS * DIN * 2);

  prep_kernel<<<2560, 256, 0, stream>>>(x, gw, gb, g, xb, w, wt);
  moe_gemm<<<512, 256, 0, stream>>>(xb, wt, g, out);
}

// Round 2
// 232.552 us; speedup vs baseline: 1.1615x; 1.0263x over previous
//
#include <hip/hip_runtime.h>
#include <hip/hip_bf16.h>
#include <cstdint>

#define TOKENS 8192
#define DIN 1024
#define DOUT 1024
#define NE 8

typedef __bf16 bf16;
typedef __attribute__((ext_vector_type(8))) __bf16 bf16x8;
typedef __attribute__((ext_vector_type(4))) float floatx4;
typedef __attribute__((ext_vector_type(2))) float floatx2;

// async global->LDS, 16B per lane. LDS dest must be wave-uniform base + lane*16.
__device__ __forceinline__ void async16(const void* gptr, void* lptr) {
  __builtin_amdgcn_global_load_lds(
      (const __attribute__((address_space(1))) void*)gptr,
      (__attribute__((address_space(3))) void*)lptr,
      16, 0, 0);
}

// ---------------------------------------------------------------------------
// Fused prep (unchanged from R7). Blocks [0,512) = gate softmax + x->bf16
// (16 tokens each, gate_w staged transposed in LDS). Blocks [512,2560) =
// W[e][i][o] fp32 -> Wt[e][o][i] bf16 transpose.
// ---------------------------------------------------------------------------
__global__ __launch_bounds__(256) void prep_kernel(
    const float* __restrict__ x, const float* __restrict__ gw,
    const float* __restrict__ gb, float* __restrict__ g,
    bf16* __restrict__ xb, const float* __restrict__ w,
    bf16* __restrict__ wt) {
  __shared__ __align__(16) float smem[NE * DIN];  // 32 KB

  if (blockIdx.x < 512) {
    const int tid = threadIdx.x;
#pragma unroll
    for (int k = 0; k < 8; ++k) {
      const int base = (k * 256 + tid) * 4;
      const floatx4 v = *(const floatx4*)(gw + base);
#pragma unroll
      for (int m = 0; m < 4; ++m) {
        const int j = base + m;
        smem[(j & 7) * DIN + (j >> 3)] = v[m];
      }
    }
    __syncthreads();

    const int lane = tid & 63;
    const int wave = tid >> 6;
#pragma unroll
    for (int tt = 0; tt < 4; ++tt) {
      const int t = blockIdx.x * 16 + wave * 4 + tt;
      const float* xr = x + (size_t)t * DIN;
      bf16* xbr = xb + (size_t)t * DIN;

      float acc[NE];
#pragma unroll
      for (int e = 0; e < NE; ++e) acc[e] = 0.f;

#pragma unroll
      for (int it = 0; it < 4; ++it) {
        const int i = it * 256 + lane * 4;
        const floatx4 xv = *(const floatx4*)(xr + i);
        union { bf16 b[4]; uint64_t u; } cv;
#pragma unroll
        for (int m = 0; m < 4; ++m) cv.b[m] = (bf16)xv[m];
        *(uint64_t*)(xbr + i) = cv.u;
#pragma unroll
        for (int e = 0; e < NE; ++e) {
          const floatx4 wv = *(const floatx4*)(smem + e * DIN + i);
          acc[e] += xv[0] * wv[0] + xv[1] * wv[1] + xv[2] * wv[2] + xv[3] * wv[3];
        }
      }
#pragma unroll
      for (int e = 0; e < NE; ++e)
#pragma unroll
        for (int off = 32; off > 0; off >>= 1)
          acc[e] += __shfl_xor(acc[e], off, 64);

      float lg[NE];
      float mx = -3.0e38f;
#pragma unroll
      for (int e = 0; e < NE; ++e) { lg[e] = acc[e] + gb[e]; mx = fmaxf(mx, lg[e]); }
      float s = 0.f;
#pragma unroll
      for (int e = 0; e < NE; ++e) { lg[e] = __expf(lg[e] - mx); s += lg[e]; }
      const float inv = 1.f / s;
      if (lane == 0) {
        floatx4 o0, o1;
#pragma unroll
        for (int e = 0; e < 4; ++e) { o0[e] = lg[e] * inv; o1[e] = lg[e + 4] * inv; }
        *(floatx4*)(g + (size_t)t * NE) = o0;
        *(floatx4*)(g + (size_t)t * NE + 4) = o1;
      }
    }
  } else {
    float (*tile)[65] = (float(*)[65])smem;
    const int b = blockIdx.x - 512;
    const int e = b >> 8;
    const int i0 = ((b >> 4) & 15) * 64;
    const int o0 = (b & 15) * 64;
    const int tid = threadIdx.x;
    const int c4 = (tid & 15) * 4;
    const int r = tid >> 4;

    const float* src = w + ((size_t)e * DIN + i0) * DOUT + o0;
#pragma unroll
    for (int rr = r; rr < 64; rr += 16) {
      const floatx4 v = *(const floatx4*)(src + (size_t)rr * DOUT + c4);
      tile[rr][c4] = v[0]; tile[rr][c4 + 1] = v[1];
      tile[rr][c4 + 2] = v[2]; tile[rr][c4 + 3] = v[3];
    }
    __syncthreads();
    bf16* dst = wt + ((size_t)e * DOUT + o0) * DIN + i0;
#pragma unroll
    for (int rr = r; rr < 64; rr += 16) {
      union { bf16 b[4]; uint64_t u; } cv;
#pragma unroll
      for (int j = 0; j < 4; ++j) cv.b[j] = (bf16)tile[c4 + j][rr];
      *(uint64_t*)(dst + (size_t)rr * DIN + c4) = cv.u;
    }
  }
}

// ---------------------------------------------------------------------------
// Fused MoE GEMM, R8: pipelined double-buffer.
// R6/R7 structure (two barriers per K-window, stage drained before compute)
// measured: wall/window 5470 cyc ~= MFMA 2483 + stage 2180 + conflicts —
// staging fully SERIAL with compute. R8: BK=64, LDS dbuf 2x(A+B)=64KB
// (still 2 blocks/CU), ONE __syncthreads per K-tile; stage of tile t+1 is
// issued between the two 16-MFMA clusters of tile t and drained only at the
// boundary (syncthreads = vmcnt(0)+barrier = exact counted wait at 1 tile in
// flight). Frag ds_reads issue BEFORE the async LDS stores (no alias-wait).
// Fragment math / swizzle / fold / C-write identical to verified R6 (row
// stride 128->64 elems, h:0..3 -> kk:0..1).
// Swizzle: unit u=tid+256j -> row=u>>3 (=srow+32j, row&7 invariant),
// phys chunk c=u&7 holds global col-group c^(row&7). Reader wants group
// kk*4+lq at phys (kk*4+lq)^(lr&7) since row&7==lr&7 for frag rows.
// ---------------------------------------------------------------------------
__global__ __launch_bounds__(256, 2) void moe_gemm(
    const bf16* __restrict__ xb, const bf16* __restrict__ wt,
    const float* __restrict__ g, float* __restrict__ out) {
  __shared__ __align__(16) bf16 As[2][128 * 64];  // 2 x 16KB
  __shared__ __align__(16) bf16 Bs[2][128 * 64];  // 2 x 16KB

  const int tid = threadIdx.x;
  // XCD swizzle on 512 blocks: c = idx&7 (XCD), jj = idx>>3 in [0,64).
  // Per-XCD chunk = 16 bm x 4 bn (same shape as R7's measured-good mapping).
  const int c = blockIdx.x & 7;
  const int jj = blockIdx.x >> 3;
  const int bm = (c >> 1) * 16 + (jj & 15);   // 0..63
  const int bn = (c & 1) * 4 + (jj >> 4);     // 0..7
  const int lane = tid & 63;
  const int wave = tid >> 6;
  const int wm = wave >> 1, wn = wave & 1;
  const int lr = lane & 15, lq = lane >> 4;

  // staging: rows have 8 16B-units now (64 cols). srow in 0..31, +32 per pass.
  const int srow = tid >> 3;
  const int scol = (((tid & 7) ^ (srow & 7)) << 3);
  const int kx = lr & 7;

  const bf16* const agp = xb + (size_t)(bm * 128 + srow) * DIN + scol;
  const bf16* const bgp = wt + (size_t)(bn * 128 + srow) * DIN + scol;

  const floatx4 fzero = {0.f, 0.f, 0.f, 0.f};
  floatx4 accF[4][4], accE[4][4];
#pragma unroll
  for (int im = 0; im < 4; ++im)
#pragma unroll
    for (int in = 0; in < 4; ++in) { accF[im][in] = fzero; accE[im][in] = fzero; }

  const int tok0 = bm * 128 + wm * 64;

  // prologue: stage tile 0 (e=0, k0=0) into buffer 0
  {
    bf16* const alp = &As[0][tid * 8];
    bf16* const blp = &Bs[0][tid * 8];
#pragma unroll
    for (int j = 0; j < 4; ++j)
      async16(agp + (size_t)(32 * j) * DIN, alp + j * 2048);
#pragma unroll
    for (int j = 0; j < 4; ++j)
      async16(bgp + (size_t)(32 * j) * DIN, blp + j * 2048);
  }
  __syncthreads();

  // 128 flattened K-tiles: t = e*16 + kt, k0 = kt*64.
  for (int t = 0; t < 128; ++t) {
    const int cur = t & 1;
    const bf16* const Ab = &As[cur][0];
    const bf16* const Bb = &Bs[cur][0];

    // 1) fragment reads for both kk halves (before any LDS stores)
    bf16x8 av[2][4], bv[2][4];
#pragma unroll
    for (int kk = 0; kk < 2; ++kk) {
      const int kg = ((kk * 4 + lq) ^ kx) << 3;
#pragma unroll
      for (int im = 0; im < 4; ++im)
        av[kk][im] = *(const bf16x8*)(Ab + (wm * 64 + im * 16 + lr) * 64 + kg);
#pragma unroll
      for (int in = 0; in < 4; ++in)
        bv[kk][in] = *(const bf16x8*)(Bb + (wn * 64 + in * 16 + lr) * 64 + kg);
    }

    // 2) stage tile t+1 (A half), overlapped with kk=0 MFMA
    const int t1 = t + 1;
    bf16* const alp = &As[cur ^ 1][tid * 8];
    bf16* const blp = &Bs[cur ^ 1][tid * 8];
    const size_t koff = (size_t)((t1 & 15) << 6);
    if (t1 < 128) {
#pragma unroll
      for (int j = 0; j < 4; ++j)
        async16(agp + koff + (size_t)(32 * j) * DIN, alp + j * 2048);
    }

    __builtin_amdgcn_s_setprio(1);
#pragma unroll
    for (int im = 0; im < 4; ++im)
#pragma unroll
      for (int in = 0; in < 4; ++in)
        accE[im][in] = __builtin_amdgcn_mfma_f32_16x16x32_bf16(
            av[0][im], bv[0][in], accE[im][in], 0, 0, 0);
    __builtin_amdgcn_s_setprio(0);

    // 3) stage tile t+1 (B half), overlapped with kk=1 MFMA
    if (t1 < 128) {
      const bf16* const bsrc = bgp + ((size_t)(t1 >> 4) << 20) + koff;
#pragma unroll
      for (int j = 0; j < 4; ++j)
        async16(bsrc + (size_t)(32 * j) * DIN, blp + j * 2048);
    }

    __builtin_amdgcn_s_setprio(1);
#pragma unroll
    for (int im = 0; im < 4; ++im)
#pragma unroll
      for (int in = 0; in < 4; ++in)
        accE[im][in] = __builtin_amdgcn_mfma_f32_16x16x32_bf16(
            av[1][im], bv[1][in], accE[im][in], 0, 0, 0);
    __builtin_amdgcn_s_setprio(0);

    // 4) expert boundary: fold accE into accF with gate weights
    if ((t & 15) == 15) {
      const int e = t >> 4;
#pragma unroll
      for (int im = 0; im < 4; ++im) {
        float gv[4];
#pragma unroll
        for (int r = 0; r < 4; ++r)
          gv[r] = g[(size_t)(tok0 + im * 16 + lq * 4 + r) * NE + e];
#pragma unroll
        for (int in = 0; in < 4; ++in)
#pragma unroll
          for (int r = 0; r < 4; ++r) {
            accF[im][in][r] += gv[r] * accE[im][in][r];
            accE[im][in][r] = 0.f;
          }
      }
    }

    // 5) boundary: vmcnt(0)+lgkmcnt(0)+barrier — tile t+1 resident after this
    __syncthreads();
  }

#pragma unroll
  for (int im = 0; im < 4; ++im)
#pragma unroll
    for (int in = 0; in < 4; ++in) {
      const int col = bn * 128 + wn * 64 + in * 16 + lr;
#pragma unroll
      for (int r = 0; r < 4; ++r)
        out[(size_t)(tok0 + im * 16 + lq * 4 + r) * DOUT + col] =
            accF[im][in][r];
    }
}

// ---------------------------------------------------------------------------
extern "C" void kernel_launch(void* const* d_in, const int* in_sizes, int n_in,
                              void* d_out, int out_size, void* d_ws,
                              size_t ws_size, hipStream_t stream) {
  const float* x  = (const float*)d_in[0];
  const float* gw = (const float*)d_in[1];
  const float* gb = (const float*)d_in[2];
  const float* w  = (const float*)d_in[3];
  float* out = (float*)d_out;

  char* ws = (char*)d_ws;
  float* g  = (float*)ws;
  bf16* xb  = (bf16*)(ws + 262144);
  bf16* wt  = (bf16*)(ws + 262144 + (size_t)TOKENS * DIN * 2);

  prep_kernel<<<2560, 256, 0, stream>>>(x, gw, gb, g, xb, w, wt);
  moe_gemm<<<512, 256, 0, stream>>>(xb, wt, g, out);
}